// Round 12
// baseline (722.394 us; speedup 1.0000x reference)
//
#include <hip/hip_runtime.h>
#include <hip/hip_bf16.h>
#include <stdint.h>

typedef __hip_bfloat16 bf16;

#define BATCH  8
#define NPG    4096
#define DIN    128
#define NH     4
#define NEDGE  262144
#define DOUTF  128
#define KORDER 4
#define NTOT   (BATCH*NPG)   // 32768
#define HD     (NH*DIN)      // 512

typedef __attribute__((ext_vector_type(8))) short short8;
typedef __attribute__((ext_vector_type(4))) float f32x4;

static __device__ __forceinline__ float b2f(bf16 v) { return __bfloat162float(v); }
static __device__ __forceinline__ float u2f(unsigned short u) {
    union { float f; unsigned int i; } c; c.i = ((unsigned int)u) << 16; return c.f;
}
static __device__ __forceinline__ unsigned short f2u(float f) {
    bf16 hb = __float2bfloat16(f);
    return *(unsigned short*)&hb;
}

// ---------------------------------------------------------------- zero
__global__ void zero_kernel(uint4* p, int n) {
    int i = blockIdx.x * 256 + threadIdx.x;
    if (i < n) p[i] = uint4{0u, 0u, 0u, 0u};
}

// ---------------------------------------------------------------- fp32 -> bf16 bulk convert
__global__ void cvtbf_kernel(const float* __restrict__ in, bf16* __restrict__ out, int n) {
    int i = (blockIdx.x * 256 + threadIdx.x) * 8;
    if (i < n) {
        float4 a = *(const float4*)(in + i);
        float4 b = *(const float4*)(in + i + 4);
        unsigned short u[8] = { f2u(a.x), f2u(a.y), f2u(a.z), f2u(a.w),
                                f2u(b.x), f2u(b.y), f2u(b.z), f2u(b.w) };
        *(uint4*)(out + i) = *(uint4*)u;
    }
}

// ---------------------------------------------------------------- projection + per-head normalize via MFMA
__global__ __launch_bounds__(256) void proj_mfma_kernel(const bf16* __restrict__ xbf,
                                                        const bf16* __restrict__ Wbf,
                                                        const float* __restrict__ bias,
                                                        bf16* __restrict__ outp,
                                                        bf16* __restrict__ outT) {
    __shared__ __align__(16) short t1[32][520];
    int n0 = blockIdx.x * 32;
    int tid = threadIdx.x;
    int lane = tid & 63, wc = tid >> 6;
    int l15 = lane & 15, quad = lane >> 4;

    f32x4 acc[2][8];
    #pragma unroll
    for (int i = 0; i < 2; i++)
        #pragma unroll
        for (int j = 0; j < 8; j++) acc[i][j] = f32x4{0.f, 0.f, 0.f, 0.f};

    #pragma unroll
    for (int ks = 0; ks < 4; ks++) {
        int kk = ks * 32 + quad * 8;
        short8 af[2];
        #pragma unroll
        for (int ti = 0; ti < 2; ti++)
            af[ti] = *(const short8*)(xbf + (size_t)(n0 + ti * 16 + l15) * DIN + kk);
        #pragma unroll
        for (int tj = 0; tj < 8; tj++) {
            short8 bfr = *(const short8*)(Wbf + (size_t)(wc * 128 + tj * 16 + l15) * DIN + kk);
            acc[0][tj] = __builtin_amdgcn_mfma_f32_16x16x32_bf16(af[0], bfr, acc[0][tj], 0, 0, 0);
            acc[1][tj] = __builtin_amdgcn_mfma_f32_16x16x32_bf16(af[1], bfr, acc[1][tj], 0, 0, 0);
        }
    }

    float bias_v[8];
    #pragma unroll
    for (int tj = 0; tj < 8; tj++) bias_v[tj] = bias[wc * 128 + tj * 16 + l15];

    #pragma unroll
    for (int ti = 0; ti < 2; ti++) {
        #pragma unroll
        for (int r = 0; r < 4; r++) {
            float s = 0.f;
            #pragma unroll
            for (int tj = 0; tj < 8; tj++) {
                float v = acc[ti][tj][r] + bias_v[tj];
                acc[ti][tj][r] = v;
                s += v * v;
            }
            s += __shfl_xor(s, 1); s += __shfl_xor(s, 2);
            s += __shfl_xor(s, 4); s += __shfl_xor(s, 8);
            float rs = rsqrtf(s);
            int node = ti * 16 + quad * 4 + r;
            #pragma unroll
            for (int tj = 0; tj < 8; tj++)
                t1[node][wc * 128 + tj * 16 + l15] = (short)f2u(acc[ti][tj][r] * rs);
        }
    }
    __syncthreads();

    if (outp) {
        #pragma unroll
        for (int u = 0; u < 8; u++) {
            int unit = u * 256 + tid;
            int nl = unit >> 6, fp = (unit & 63) * 8;
            *(uint4*)(outp + (size_t)(n0 + nl) * HD + fp) = *(uint4*)&t1[nl][fp];
        }
    }
    if (outT) {
        int b = n0 >> 12, nl0 = n0 & 4095;
        #pragma unroll
        for (int u = 0; u < 8; u++) {
            int unit = u * 256 + tid;
            int f = unit >> 2, np = (unit & 3) * 8;
            unsigned short arr[8];
            #pragma unroll
            for (int j = 0; j < 8; j++) arr[j] = (unsigned short)t1[np + j][f];
            *(uint4*)(outT + ((size_t)b * HD + f) * NPG + nl0 + np) = *(uint4*)arr;
        }
    }
}

// ---------------------------------------------------------------- degree
__global__ void deg_kernel(const int* __restrict__ row, int* __restrict__ deg) {
    int e = blockIdx.x * 256 + threadIdx.x;
    if (e < NEDGE) atomicAdd(&deg[row[e]], 1);
}

__global__ void dis_kernel(const int* __restrict__ deg, float* __restrict__ dis) {
    int i = blockIdx.x * 256 + threadIdx.x;
    if (i < NTOT) {
        int d = deg[i];
        dis[i] = d > 0 ? rsqrtf((float)d) : 0.f;
    }
}

// ---------------------------------------------------------------- multi-block exclusive scan
__global__ __launch_bounds__(1024) void scan1_kernel(const int* __restrict__ deg,
                                                     int* __restrict__ row_ptr, int* __restrict__ bsum) {
    __shared__ int buf[1024];
    int g = blockIdx.x, t = threadIdx.x;
    int v = deg[g * 1024 + t];
    buf[t] = v;
    __syncthreads();
    for (int off = 1; off < 1024; off <<= 1) {
        int add = (t >= off) ? buf[t - off] : 0;
        __syncthreads();
        buf[t] += add;
        __syncthreads();
    }
    row_ptr[g * 1024 + t] = buf[t] - v;
    if (t == 1023) bsum[g] = buf[1023];
}

__global__ void scan2_kernel(const int* __restrict__ bsum, int* __restrict__ boff, int* __restrict__ row_ptr,
                             int* __restrict__ cnt) {
    int run = 0;
    for (int g = 0; g < 32; g++) { boff[g] = run; run += bsum[g]; cnt[g] = 0; }
    row_ptr[NTOT] = run;
}

__global__ __launch_bounds__(1024) void scan3_kernel(int* __restrict__ row_ptr, const int* __restrict__ boff) {
    row_ptr[blockIdx.x * 1024 + threadIdx.x] += boff[blockIdx.x];
}

// ---------------------------------------------------------------- per-tile degree argsort (bitonic, 128 nodes/tile)
__global__ __launch_bounds__(128) void sortperm_kernel(const int* __restrict__ row_ptr,
                                                       int* __restrict__ perm) {
    __shared__ int key[128];
    __shared__ int val[128];
    int tile = blockIdx.x;
    int t = threadIdx.x;
    int n = tile * 128 + t;
    key[t] = row_ptr[n + 1] - row_ptr[n];
    val[t] = t;
    __syncthreads();
    for (int k = 2; k <= 128; k <<= 1) {
        for (int j = k >> 1; j > 0; j >>= 1) {
            int ixj = t ^ j;
            if (ixj > t) {
                int a = key[t], b = key[ixj];
                bool up = ((t & k) == 0);
                if ((a > b) == up) {
                    key[t] = b; key[ixj] = a;
                    int va = val[t]; val[t] = val[ixj]; val[ixj] = va;
                }
            }
            __syncthreads();
        }
    }
    perm[tile * 128 + t] = val[t];
}

// ---------------------------------------------------------------- CSR scatter (packed col+weight)
__global__ void scatter_kernel(const int* __restrict__ row, const int* __restrict__ col,
                               const int* __restrict__ row_ptr, int* __restrict__ fill,
                               const float* __restrict__ dis,
                               uint2* __restrict__ ecw) {
    int e = blockIdx.x * 256 + threadIdx.x;
    if (e < NEDGE) {
        int r = row[e], c = col[e];
        int pos = row_ptr[r] + atomicAdd(&fill[r], 1);
        ecw[pos] = uint2{(unsigned)c, __float_as_uint(dis[c])};
    }
}

// ---------------------------------------------------------------- row sums over transposed layout (ksum)
__global__ __launch_bounds__(256) void rowsum_kernel(const bf16* __restrict__ T, float* __restrict__ out) {
    int row = blockIdx.x * 4 + (threadIdx.x >> 6);
    int lane = threadIdx.x & 63;
    const ushort4* p = (const ushort4*)(T + (size_t)row * NPG);
    float s = 0.f;
    #pragma unroll
    for (int wv = 0; wv < 16; wv++) {
        ushort4 u = p[lane + wv * 64];
        s += u2f(u.x) + u2f(u.y) + u2f(u.z) + u2f(u.w);
    }
    for (int off = 32; off > 0; off >>= 1) s += __shfl_down(s, off);
    if (lane == 0) out[row] = s;
}

// ---------------------------------------------------------------- vsum0: column sums over xbf (broadcast to heads)
__global__ __launch_bounds__(256) void colsum_kernel(const bf16* __restrict__ xbf, float* __restrict__ vsum) {
    __shared__ float buf[256];
    int b = blockIdx.x >> 3, sl = blockIdx.x & 7;
    int t = threadIdx.x;
    int d = t & 127, half = t >> 7;
    const unsigned short* p = (const unsigned short*)xbf + ((size_t)b * NPG + sl * 512 + half * 256) * DIN + d;
    float s = 0.f;
    for (int r = 0; r < 256; r++) s += u2f(p[(size_t)r * DIN]);
    buf[t] = s;
    __syncthreads();
    if (half == 0) {
        float tot = buf[d] + buf[d + 128];
        #pragma unroll
        for (int h = 0; h < NH; h++) atomicAdd(&vsum[b * HD + h * DIN + d], tot);
    }
}

// ---------------------------------------------------------------- rden = 1/(qs . ksum + n)
__global__ __launch_bounds__(256) void den_kernel(const bf16* __restrict__ qs, const float* __restrict__ ksum,
                                                  const int* __restrict__ n_nodes, float* __restrict__ rden) {
    int n = blockIdx.x;
    int b = n >> 12;
    int w = threadIdx.x >> 6, lane = threadIdx.x & 63;
    int base = w * DIN;
    float p = b2f(qs[(size_t)n * HD + base + lane])      * ksum[b * HD + base + lane]
            + b2f(qs[(size_t)n * HD + base + 64 + lane]) * ksum[b * HD + base + 64 + lane];
    for (int off = 32; off > 0; off >>= 1) p += __shfl_down(p, off);
    if (lane == 0) rden[n * NH + w] = 1.0f / (p + (float)n_nodes[b]);
}

// ---------------------------------------------------------------- kv via MFMA: split-K partials + fused last-block reduction
// v3: each (b,h) has KVSPLIT split blocks; the 16th to finish (device-scope counter,
//     release/acquire __threadfence) reduces partials -> kvB and resets cnt[bh].
//     Removes the separate kvredB dispatch (1 launch/iter). Block 0 zeroes vsumN
//     (consumed only by the NEXT kernel in the stream).
//     round-10 lesson: direct atomicAdd accumulation is 50us WORSE (cross-XCD atomic
//     serialization) — streamed partials + single-reader reduction is the fast shape.
#define KVSPLIT 16
__global__ __launch_bounds__(512, 4) void kv_mfma_kernel(const bf16* __restrict__ ksT,
                                                         const bf16* __restrict__ vsrc,
                                                         int vld, int vhm,
                                                         float* __restrict__ partial,
                                                         bf16* __restrict__ kvB,
                                                         int* __restrict__ cnt,
                                                         float* __restrict__ vsumN) {
    __shared__ __align__(16) short kshT[128][72];
    __shared__ __align__(16) short vshT[128][72];
    __shared__ int isLast;
    int id = blockIdx.x;
    int b = id & 7;
    int u = id >> 3;
    int h = u >> 4;
    int s = u & 15;
    int bh = b * 4 + h;
    int blk = bh * KVSPLIT + s;
    int tid = threadIdx.x;
    int lane = tid & 63;
    int w = tid >> 6;
    int wr = w >> 1, wc = w & 1;
    int d0w = wr * 32, e0w = wc * 64;
    int l15 = lane & 15, quad = lane >> 4;

    // fused: zero next-iter vsum accumulator (used only by the subsequent gcn_attn dispatch)
    if (id == 0) {
        ((uint4*)vsumN)[tid] = uint4{0u, 0u, 0u, 0u};
        ((uint4*)vsumN)[512 + tid] = uint4{0u, 0u, 0u, 0u};
    }

    f32x4 acc[2][4];
    #pragma unroll
    for (int i = 0; i < 2; i++)
        #pragma unroll
        for (int j = 0; j < 4; j++) acc[i][j] = f32x4{0.f, 0.f, 0.f, 0.f};

    const uint4* kg = (const uint4*)(ksT + ((size_t)bh * 128) * NPG);
    const bf16* vg = vsrc + (size_t)h * vhm;
    int n0 = s * (NPG / KVSPLIT);

    for (int c = 0; c < NPG / KVSPLIT / 64; c++) {
        int nb = n0 + c * 64;
        #pragma unroll
        for (int uu = 0; uu < 2; uu++) {
            int unit = uu * 512 + tid;
            int row = unit >> 3;
            int part = unit & 7;
            uint4 kd = kg[row * (NPG / 8) + (nb >> 3) + part];
            *(uint4*)&kshT[row][part * 8] = kd;
            int nl = unit >> 4;
            int fg = unit & 15;
            uint4 vd = *(const uint4*)(vg + (size_t)(b * NPG + nb + nl) * vld + fg * 8);
            unsigned short* sv = (unsigned short*)&vd;
            int ncol = nl ^ ((fg & 7) << 3);
            #pragma unroll
            for (int j = 0; j < 8; j++) vshT[fg * 8 + j][ncol] = (short)sv[j];
        }
        __syncthreads();
        #pragma unroll
        for (int kkstep = 0; kkstep < 2; kkstep++) {
            int kk = kkstep * 32 + quad * 8;
            short8 af[2], bfr[4];
            #pragma unroll
            for (int ti = 0; ti < 2; ti++)
                af[ti] = *(const short8*)&kshT[d0w + ti * 16 + l15][kk];
            #pragma unroll
            for (int tj = 0; tj < 4; tj++) {
                int e = e0w + tj * 16 + l15;
                bfr[tj] = *(const short8*)&vshT[e][kk ^ (((e >> 3) & 7) << 3)];
            }
            #pragma unroll
            for (int ti = 0; ti < 2; ti++)
                #pragma unroll
                for (int tj = 0; tj < 4; tj++)
                    acc[ti][tj] = __builtin_amdgcn_mfma_f32_16x16x32_bf16(af[ti], bfr[tj], acc[ti][tj], 0, 0, 0);
        }
        __syncthreads();
    }
    float* p = partial + (size_t)blk * (128 * 128);
    #pragma unroll
    for (int ti = 0; ti < 2; ti++)
        #pragma unroll
        for (int tj = 0; tj < 4; tj++)
            #pragma unroll
            for (int r = 0; r < 4; r++) {
                int row = d0w + ti * 16 + quad * 4 + r;
                int col = e0w + tj * 16 + l15;
                p[row * 128 + col] = acc[ti][tj][r];
            }

    // --- last-block reduction: 16th finisher of this bh reduces partials -> kvB ---
    __syncthreads();                       // all vmem drained (compiler waitcnt before barrier)
    if (tid == 0) {
        __threadfence();                   // release: make our partial stores device-visible
        int old = atomicAdd(&cnt[bh], 1);
        isLast = (old == KVSPLIT - 1);
    }
    __syncthreads();
    if (!isLast) return;
    if (tid == 0) __threadfence();         // acquire: invalidate stale cached partial lines
    __syncthreads();

    short (*tt)[136] = (short(*)[136])kshT;  // reuse LDS as 16x136 transpose tile
    const float* pp = partial + (size_t)bh * (KVSPLIT * 16384);
    for (int e0c = 0; e0c < 8; e0c++) {
        if (tid < 256) {
            int el = tid & 15;
            int dc = tid >> 4;
            #pragma unroll
            for (int j = 0; j < 8; j++) {
                int d = dc * 8 + j;
                int idx = d * 128 + e0c * 16 + el;
                float sum = 0.f;
                #pragma unroll
                for (int sl = 0; sl < KVSPLIT; sl++) sum += pp[sl * 16384 + idx];
                tt[el][d] = (short)f2u(sum);
            }
        }
        __syncthreads();
        if (tid < 256) {
            int e = tid >> 4, dp = (tid & 15) * 8;
            *(uint4*)((unsigned short*)kvB + (size_t)bh * 16384 + (e0c * 16 + e) * 128 + dp) = *(uint4*)&tt[e][dp];
        }
        __syncthreads();
    }
    if (tid == 0) cnt[bh] = 0;             // reset for next dispatch (kernel boundary flushes)
}

// ---------------------------------------------------------------- gather FMA helper
static __device__ __forceinline__ void acc8(float* g, uint4 v, float w) {
    unsigned short* sv = (unsigned short*)&v;
    #pragma unroll
    for (int k = 0; k < 8; k++) g[k] += w * u2f(sv[k]);
}

// ---------------------------------------------------------------- fused GCN-gather + attn MFMA + combine + store
// PROVEN BEST (round-5/11: 55us/dispatch). 2-deep pipeline, 4 thr/node, 128 nodes/block,
// est staging EMAX 1536, degree-sort perm, lb(512,2).
// Locked lessons: lb(512,6) spills (r3); no est staging +7us (r6); 8 thr/node -35% (r7);
// 4-deep pipeline -> VGPR 96 -> 2 blk/CU -21% (r8); NT hints +8us (r9); kv atomics +50us (r10).
#define EMAX 1536
__global__ __launch_bounds__(512, 2) void gcn_attn_kernel(const bf16* __restrict__ qs,
                                                          const bf16* __restrict__ kvB,
                                                          const bf16* __restrict__ gsrc,
                                                          int gld, int ghm,
                                                          const int* __restrict__ row_ptr,
                                                          const int* __restrict__ perm,
                                                          const uint2* __restrict__ ecw,
                                                          const float* __restrict__ dis,
                                                          const float* __restrict__ vsum,   // current iter
                                                          const float* __restrict__ rden,
                                                          bf16* __restrict__ curN,
                                                          float* __restrict__ vsumN) {      // next iter (atomic)
    __shared__ __align__(16) short t1[128][136];
    __shared__ __align__(8) uint2 est[EMAX];
    int id = blockIdx.x;
    int b = id & 7;
    int u = id >> 3;
    int h = u >> 5;
    int m = u & 31;
    int bh = b * 4 + h;
    int n0 = b * NPG + m * 128;
    int tid = threadIdx.x;
    int lane = tid & 63, w = tid >> 6;
    int wr = w >> 1, wc = w & 1;
    int e0w = wc * 64;
    int l15 = lane & 15, quad = lane >> 4;

    // phase A0: stage this block's edge list into LDS (coalesced)
    int ebase = row_ptr[n0];
    int ecnt = row_ptr[n0 + 128] - ebase;
    int scnt = ecnt < EMAX ? ecnt : EMAX;
    for (int i = tid; i < scnt; i += 512) est[i] = ecw[ebase + i];
    __syncthreads();

    // phase A: GCN gather, 2-edge-deep pipelined, nodes in ascending-degree order
    {
        int nl = perm[n0 + (tid >> 2)];
        int sub = tid & 3;
        int n = n0 + nl;
        int start = row_ptr[n] - ebase;
        int end   = row_ptr[n + 1] - ebase;
        int lend  = end < scnt ? end : scnt;
        float g[32];
        #pragma unroll
        for (int i = 0; i < 32; i++) g[i] = 0.f;
        const bf16* gbase = gsrc + (size_t)h * ghm + sub * 32;

        int cA = 0, cB = 0; float wA = 0.f, wB = 0.f;
        if (start < lend)     { uint2 p = est[start];     cA = (int)p.x; wA = __uint_as_float(p.y); }
        if (start + 1 < lend) { uint2 p = est[start + 1]; cB = (int)p.x; wB = __uint_as_float(p.y); }
        uint4 vA0, vA1, vA2, vA3, vB0, vB1, vB2, vB3;
        {
            const uint4* p = (const uint4*)(gbase + (size_t)cA * gld);
            vA0 = p[0]; vA1 = p[1]; vA2 = p[2]; vA3 = p[3];
        }
        {
            const uint4* p = (const uint4*)(gbase + (size_t)cB * gld);
            vB0 = p[0]; vB1 = p[1]; vB2 = p[2]; vB3 = p[3];
        }
        for (int j = start; j < lend; j += 2) {
            int cC = 0, cD = 0; float wC = 0.f, wD = 0.f;
            if (j + 2 < lend) { uint2 p = est[j + 2]; cC = (int)p.x; wC = __uint_as_float(p.y); }
            if (j + 3 < lend) { uint2 p = est[j + 3]; cD = (int)p.x; wD = __uint_as_float(p.y); }
            acc8(g +  0, vA0, wA); acc8(g +  8, vA1, wA);
            acc8(g + 16, vA2, wA); acc8(g + 24, vA3, wA);
            {
                const uint4* p = (const uint4*)(gbase + (size_t)cC * gld);
                vA0 = p[0]; vA1 = p[1]; vA2 = p[2]; vA3 = p[3];
            }
            acc8(g +  0, vB0, wB); acc8(g +  8, vB1, wB);
            acc8(g + 16, vB2, wB); acc8(g + 24, vB3, wB);
            {
                const uint4* p = (const uint4*)(gbase + (size_t)cD * gld);
                vB0 = p[0]; vB1 = p[1]; vB2 = p[2]; vB3 = p[3];
            }
            wA = wC; wB = wD;
        }
        int fstart = start > lend ? start : lend;
        for (int j = fstart; j < end; j++) {
            uint2 pe = ecw[ebase + j];
            int c = (int)pe.x; float ww = __uint_as_float(pe.y);
            const uint4* p = (const uint4*)(gbase + (size_t)c * gld);
            acc8(g +  0, p[0], ww); acc8(g +  8, p[1], ww);
            acc8(g + 16, p[2], ww); acc8(g + 24, p[3], ww);
        }

        float dn = dis[n];
        int sw = (nl >> 3) & 7;
        #pragma unroll
        for (int q = 0; q < 4; q++) {
            unsigned short arr[8];
            #pragma unroll
            for (int k = 0; k < 8; k++) arr[k] = f2u(g[q * 8 + k] * dn);
            int fb = (sub * 4 + q) ^ sw;
            *(uint4*)&t1[nl][fb * 8] = *(uint4*)arr;
        }
    }

    // phase B: MFMA q . kv (independent of t1)
    f32x4 acc[2][4];
    #pragma unroll
    for (int i = 0; i < 2; i++)
        #pragma unroll
        for (int j = 0; j < 4; j++) acc[i][j] = f32x4{0.f, 0.f, 0.f, 0.f};

    const bf16* Aq = qs + (size_t)n0 * HD + h * DIN;
    const unsigned short* Bk = (const unsigned short*)kvB + (size_t)bh * 16384;
    #pragma unroll
    for (int ks = 0; ks < 4; ks++) {
        int kk = ks * 32 + quad * 8;
        short8 af[2], bfr[4];
        #pragma unroll
        for (int ti = 0; ti < 2; ti++)
            af[ti] = *(const short8*)(Aq + (size_t)(wr * 32 + ti * 16 + l15) * HD + kk);
        #pragma unroll
        for (int tj = 0; tj < 4; tj++)
            bfr[tj] = *(const short8*)(Bk + (e0w + tj * 16 + l15) * 128 + kk);
        #pragma unroll
        for (int ti = 0; ti < 2; ti++)
            #pragma unroll
            for (int tj = 0; tj < 4; tj++)
                acc[ti][tj] = __builtin_amdgcn_mfma_f32_16x16x32_bf16(af[ti], bfr[tj], acc[ti][tj], 0, 0, 0);
    }
    __syncthreads();

    // phase C: combine + register-level column sums for next-iter vsum
    #pragma unroll
    for (int tj = 0; tj < 4; tj++) {
        int el = e0w + tj * 16 + l15;
        float vs = vsum[b * HD + h * DIN + el];
        float cs = 0.f;
        #pragma unroll
        for (int ti = 0; ti < 2; ti++) {
            int nlb = wr * 32 + ti * 16 + quad * 4;
            #pragma unroll
            for (int r = 0; r < 4; r++) {
                int nl = nlb + r;
                int sw = (nl >> 3) & 7;
                int pc = (((el >> 3) ^ sw) * 8) | (el & 7);
                float attnv = (acc[ti][tj][r] + vs) * rden[(size_t)(n0 + nl) * NH + h];
                float g = u2f((unsigned short)t1[nl][pc]);
                float val = 0.5f * g + 0.5f * attnv;
                t1[nl][pc] = (short)f2u(val);
                cs += val;
            }
        }
        cs += __shfl_xor(cs, 16);
        cs += __shfl_xor(cs, 32);
        if (quad == 0) atomicAdd(&vsumN[b * HD + h * DIN + el], cs);
    }
    __syncthreads();

    // phase D: curN store only
    {
        bf16* dstn = curN + (size_t)n0 * HD + h * DIN;
        #pragma unroll
        for (int uu = 0; uu < 4; uu++) {
            int unit = uu * 512 + tid;
            int nl = unit >> 4, fb = unit & 15;
            int sw = (nl >> 3) & 7;
            uint4 v = *(uint4*)&t1[nl][(fb ^ sw) * 8];
            *(uint4*)(dstn + (size_t)nl * HD + fb * 8) = v;
        }
    }
}

// ---------------------------------------------------------------- output projection via MFMA, fused acc = xh + sum(cur_k)
__global__ __launch_bounds__(256, 4) void out_mfma_kernel(const bf16* __restrict__ xbf,
                                                          const bf16* __restrict__ c1,
                                                          const bf16* __restrict__ c2,
                                                          const bf16* __restrict__ c3,
                                                          const bf16* __restrict__ c4,
                                                          const bf16* __restrict__ Wobf,
                                                          const float* __restrict__ Wo_b,
                                                          float* __restrict__ out) {
    __shared__ __align__(16) short ash[32][520];
    int n0 = blockIdx.x * 32;
    int tid = threadIdx.x;
    int lane = tid & 63, w = tid >> 6;
    int l15 = lane & 15, quad = lane >> 4;

    #pragma unroll 4
    for (int uu = 0; uu < 8; uu++) {
        int unit = uu * 256 + tid;
        int row = unit >> 6, cg = unit & 63;
        int col = cg * 8;
        size_t rbase = (size_t)(n0 + row);
        uint4 vx = *(const uint4*)(xbf + rbase * DIN + (col & 127));
        uint4 v1 = *(const uint4*)(c1 + rbase * HD + col);
        uint4 v2 = *(const uint4*)(c2 + rbase * HD + col);
        uint4 v3 = *(const uint4*)(c3 + rbase * HD + col);
        uint4 v4 = *(const uint4*)(c4 + rbase * HD + col);
        unsigned short* px = (unsigned short*)&vx;
        unsigned short* p1 = (unsigned short*)&v1;
        unsigned short* p2 = (unsigned short*)&v2;
        unsigned short* p3 = (unsigned short*)&v3;
        unsigned short* p4 = (unsigned short*)&v4;
        unsigned short o[8];
        #pragma unroll
        for (int j = 0; j < 8; j++)
            o[j] = f2u(u2f(px[j]) + u2f(p1[j]) + u2f(p2[j]) + u2f(p3[j]) + u2f(p4[j]));
        *(uint4*)&ash[row][col] = *(uint4*)o;
    }
    __syncthreads();

    f32x4 acc[2][2];
    #pragma unroll
    for (int i = 0; i < 2; i++)
        #pragma unroll
        for (int j = 0; j < 2; j++) acc[i][j] = f32x4{0.f, 0.f, 0.f, 0.f};

    #pragma unroll
    for (int ks = 0; ks < 16; ks++) {
        int kk = ks * 32 + quad * 8;
        short8 af[2], bfr[2];
        #pragma unroll
        for (int ti = 0; ti < 2; ti++)
            af[ti] = *(const short8*)&ash[ti * 16 + l15][kk];
        #pragma unroll
        for (int tj = 0; tj < 2; tj++)
            bfr[tj] = *(const short8*)(Wobf + (size_t)(w * 32 + tj * 16 + l15) * HD + kk);
        #pragma unroll
        for (int ti = 0; ti < 2; ti++)
            #pragma unroll
            for (int tj = 0; tj < 2; tj++)
                acc[ti][tj] = __builtin_amdgcn_mfma_f32_16x16x32_bf16(af[ti], bfr[tj], acc[ti][tj], 0, 0, 0);
    }

    #pragma unroll
    for (int tj = 0; tj < 2; tj++) {
        int col = w * 32 + tj * 16 + l15;
        float bv = Wo_b[col];
        #pragma unroll
        for (int ti = 0; ti < 2; ti++) {
            int rowb = ti * 16 + quad * 4;
            #pragma unroll
            for (int r = 0; r < 4; r++)
                out[(size_t)(n0 + rowb + r) * DOUTF + col] = (acc[ti][tj][r] + bv) * 0.25f;
        }
    }
}

// ================================================================ launch
extern "C" void kernel_launch(void* const* d_in, const int* in_sizes, int n_in,
                              void* d_out, int out_size, void* d_ws, size_t ws_size,
                              hipStream_t stream) {
    const float* x     = (const float*)d_in[0];
    const float* Wq_w  = (const float*)d_in[1];
    const float* Wq_b  = (const float*)d_in[2];
    const float* Wk_w  = (const float*)d_in[3];
    const float* Wk_b  = (const float*)d_in[4];
    const float* Wo_w  = (const float*)d_in[5];
    const float* Wo_b  = (const float*)d_in[6];
    const int*   edge  = (const int*)d_in[7];
    const int*   n_nod = (const int*)d_in[8];
    float* out = (float*)d_out;
    const int* erow = edge;
    const int* ecol = edge + NEDGE;

    char* w = (char*)d_ws;
    auto alloc = [&](size_t bytes) -> char* {
        char* p = w;
        w += (bytes + 255) & ~(size_t)255;
        return p;
    };
    bf16*  qs      = (bf16*) alloc((size_t)NTOT * HD * 2);            // 32 MiB
    bf16*  ksT     = (bf16*) alloc((size_t)NTOT * HD * 2);            // 32 MiB
    bf16*  cur1    = (bf16*) alloc((size_t)NTOT * HD * 2);            // 32 MiB
    bf16*  cur2    = (bf16*) alloc((size_t)NTOT * HD * 2);            // 32 MiB
    bf16*  cur3    = (bf16*) alloc((size_t)NTOT * HD * 2);            // 32 MiB
    bf16*  cur4    = (bf16*) alloc((size_t)NTOT * HD * 2);            // 32 MiB
    bf16*  xbf     = (bf16*) alloc((size_t)NTOT * DIN * 2);           // 8 MiB (persistent)
    float* partial = (float*)alloc((size_t)32 * KVSPLIT * 16384 * 4); // 32 MiB (aliased in setup)
    bf16*  kvB     = (bf16*) alloc((size_t)32 * 16384 * 2);           // 1 MiB
    bf16*  Wobf    = (bf16*) alloc(DOUTF * HD * 2);                   // 128 KiB
    int*   degfill = (int*)  alloc(2 * NTOT * 4);
    float* dis     = (float*)alloc(NTOT * 4);
    int*   row_ptr = (int*)  alloc((NTOT + 1) * 4);
    int*   perm    = (int*)  alloc(NTOT * 4);
    uint2* ecw     = (uint2*)alloc((size_t)NEDGE * 8);
    float* ksum    = (float*)alloc(BATCH * HD * 4);
    float* vsumA   = (float*)alloc(BATCH * HD * 4);
    float* vsumB   = (float*)alloc(BATCH * HD * 4);
    float* rden    = (float*)alloc((size_t)NTOT * NH * 4);
    int*   bsum    = (int*)  alloc(32 * 4);
    int*   boff    = (int*)  alloc(32 * 4);
    int*   cnt     = (int*)  alloc(32 * 4);
    int* deg  = degfill;
    int* fill = degfill + NTOT;
    // setup-only weight buffers aliased onto partial (dead before first kv_mfma)
    bf16* Wqbf = (bf16*)partial;
    bf16* Wkbf = Wqbf + (size_t)HD * DIN;
    // total ~216 MiB

    zero_kernel<<<64, 256, 0, stream>>>((uint4*)degfill, 2 * NTOT / 4);

    cvtbf_kernel<<<NTOT * DIN / 8 / 256, 256, 0, stream>>>(x, xbf, NTOT * DIN);
    cvtbf_kernel<<<HD * DIN / 8 / 256, 256, 0, stream>>>(Wq_w, Wqbf, HD * DIN);
    cvtbf_kernel<<<HD * DIN / 8 / 256, 256, 0, stream>>>(Wk_w, Wkbf, HD * DIN);
    cvtbf_kernel<<<DOUTF * HD / 8 / 256, 256, 0, stream>>>(Wo_w, Wobf, DOUTF * HD);

    proj_mfma_kernel<<<NTOT / 32, 256, 0, stream>>>(xbf, Wqbf, Wq_b, qs, (bf16*)nullptr);
    proj_mfma_kernel<<<NTOT / 32, 256, 0, stream>>>(xbf, Wkbf, Wk_b, (bf16*)nullptr, ksT);

    deg_kernel<<<NEDGE / 256, 256, 0, stream>>>(erow, deg);
    dis_kernel<<<NTOT / 256, 256, 0, stream>>>(deg, dis);
    scan1_kernel<<<32, 1024, 0, stream>>>(deg, row_ptr, bsum);
    scan2_kernel<<<1, 1, 0, stream>>>(bsum, boff, row_ptr, cnt);
    scan3_kernel<<<32, 1024, 0, stream>>>(row_ptr, boff);
    sortperm_kernel<<<NTOT / 128, 128, 0, stream>>>(row_ptr, perm);
    scatter_kernel<<<NEDGE / 256, 256, 0, stream>>>(erow, ecol, row_ptr, fill, dis, ecw);

    rowsum_kernel<<<BATCH * HD / 4, 256, 0, stream>>>(ksT, ksum);
    den_kernel<<<NTOT, 256, 0, stream>>>(qs, ksum, n_nod, rden);

    zero_kernel<<<4, 256, 0, stream>>>((uint4*)vsumA, BATCH * HD / 4);
    colsum_kernel<<<64, 256, 0, stream>>>(xbf, vsumA);

    bf16* curs[4] = { cur1, cur2, cur3, cur4 };
    float* vs = vsumA;
    float* vsN = vsumB;
    for (int it = 0; it < KORDER; it++) {
        const bf16* src = (it == 0) ? xbf : curs[it - 1];
        int ld = (it == 0) ? DIN : HD;
        int hm = (it == 0) ? 0 : DIN;
        kv_mfma_kernel<<<32 * KVSPLIT, 512, 0, stream>>>(ksT, src, ld, hm, partial, kvB, cnt, vsN);
        gcn_attn_kernel<<<32 * 32, 512, 0, stream>>>(qs, kvB, src, ld, hm, row_ptr, perm, ecw, dis,
                                                     vs, rden, curs[it], vsN);
        float* tf = vs; vs = vsN; vsN = tf;
    }

    out_mfma_kernel<<<NTOT / 32, 256, 0, stream>>>(xbf, cur1, cur2, cur3, cur4, Wobf, Wo_b, out);

    (void)in_sizes; (void)n_in; (void)out_size; (void)ws_size;
}

// Round 13
// 546.115 us; speedup vs baseline: 1.3228x; 1.3228x over previous
//
#include <hip/hip_runtime.h>
#include <hip/hip_bf16.h>
#include <stdint.h>

typedef __hip_bfloat16 bf16;

#define BATCH  8
#define NPG    4096
#define DIN    128
#define NH     4
#define NEDGE  262144
#define DOUTF  128
#define KORDER 4
#define NTOT   (BATCH*NPG)   // 32768
#define HD     (NH*DIN)      // 512

typedef __attribute__((ext_vector_type(8))) short short8;
typedef __attribute__((ext_vector_type(4))) float f32x4;

static __device__ __forceinline__ float b2f(bf16 v) { return __bfloat162float(v); }
static __device__ __forceinline__ float u2f(unsigned short u) {
    union { float f; unsigned int i; } c; c.i = ((unsigned int)u) << 16; return c.f;
}
static __device__ __forceinline__ unsigned short f2u(float f) {
    bf16 hb = __float2bfloat16(f);
    return *(unsigned short*)&hb;
}

// ---------------------------------------------------------------- fp32 -> bf16 bulk convert (+ optional zero-fill tail blocks)
__global__ void cvtbf_zero_kernel(const float* __restrict__ in, bf16* __restrict__ out, int n,
                                  int cblk, uint4* __restrict__ zp, int zn) {
    int bid = blockIdx.x;
    if (bid < cblk) {
        int i = (bid * 256 + threadIdx.x) * 8;
        if (i < n) {
            float4 a = *(const float4*)(in + i);
            float4 b = *(const float4*)(in + i + 4);
            unsigned short u[8] = { f2u(a.x), f2u(a.y), f2u(a.z), f2u(a.w),
                                    f2u(b.x), f2u(b.y), f2u(b.z), f2u(b.w) };
            *(uint4*)(out + i) = *(uint4*)u;
        }
    } else {
        int i = (bid - cblk) * 256 + threadIdx.x;
        if (i < zn) zp[i] = uint4{0u, 0u, 0u, 0u};
    }
}

__global__ void cvtbf_kernel(const float* __restrict__ in, bf16* __restrict__ out, int n) {
    int i = (blockIdx.x * 256 + threadIdx.x) * 8;
    if (i < n) {
        float4 a = *(const float4*)(in + i);
        float4 b = *(const float4*)(in + i + 4);
        unsigned short u[8] = { f2u(a.x), f2u(a.y), f2u(a.z), f2u(a.w),
                                f2u(b.x), f2u(b.y), f2u(b.z), f2u(b.w) };
        *(uint4*)(out + i) = *(uint4*)u;
    }
}

// ---------------------------------------------------------------- Q+K projection + per-head normalize via MFMA (fused: one launch)
__global__ __launch_bounds__(256) void proj2_mfma_kernel(const bf16* __restrict__ xbf,
                                                         const bf16* __restrict__ Wq,
                                                         const float* __restrict__ bq,
                                                         bf16* __restrict__ qs,
                                                         const bf16* __restrict__ Wk,
                                                         const float* __restrict__ bk,
                                                         bf16* __restrict__ ksT) {
    __shared__ __align__(16) short t1[32][520];
    bool isQ = blockIdx.x < (NTOT / 32);
    int blk = isQ ? blockIdx.x : blockIdx.x - NTOT / 32;
    const bf16* Wbf = isQ ? Wq : Wk;
    const float* bias = isQ ? bq : bk;
    int n0 = blk * 32;
    int tid = threadIdx.x;
    int lane = tid & 63, wc = tid >> 6;
    int l15 = lane & 15, quad = lane >> 4;

    f32x4 acc[2][8];
    #pragma unroll
    for (int i = 0; i < 2; i++)
        #pragma unroll
        for (int j = 0; j < 8; j++) acc[i][j] = f32x4{0.f, 0.f, 0.f, 0.f};

    #pragma unroll
    for (int ks = 0; ks < 4; ks++) {
        int kk = ks * 32 + quad * 8;
        short8 af[2];
        #pragma unroll
        for (int ti = 0; ti < 2; ti++)
            af[ti] = *(const short8*)(xbf + (size_t)(n0 + ti * 16 + l15) * DIN + kk);
        #pragma unroll
        for (int tj = 0; tj < 8; tj++) {
            short8 bfr = *(const short8*)(Wbf + (size_t)(wc * 128 + tj * 16 + l15) * DIN + kk);
            acc[0][tj] = __builtin_amdgcn_mfma_f32_16x16x32_bf16(af[0], bfr, acc[0][tj], 0, 0, 0);
            acc[1][tj] = __builtin_amdgcn_mfma_f32_16x16x32_bf16(af[1], bfr, acc[1][tj], 0, 0, 0);
        }
    }

    float bias_v[8];
    #pragma unroll
    for (int tj = 0; tj < 8; tj++) bias_v[tj] = bias[wc * 128 + tj * 16 + l15];

    #pragma unroll
    for (int ti = 0; ti < 2; ti++) {
        #pragma unroll
        for (int r = 0; r < 4; r++) {
            float s = 0.f;
            #pragma unroll
            for (int tj = 0; tj < 8; tj++) {
                float v = acc[ti][tj][r] + bias_v[tj];
                acc[ti][tj][r] = v;
                s += v * v;
            }
            s += __shfl_xor(s, 1); s += __shfl_xor(s, 2);
            s += __shfl_xor(s, 4); s += __shfl_xor(s, 8);
            float rs = rsqrtf(s);
            int node = ti * 16 + quad * 4 + r;
            #pragma unroll
            for (int tj = 0; tj < 8; tj++)
                t1[node][wc * 128 + tj * 16 + l15] = (short)f2u(acc[ti][tj][r] * rs);
        }
    }
    __syncthreads();

    if (isQ) {
        #pragma unroll
        for (int u = 0; u < 8; u++) {
            int unit = u * 256 + tid;
            int nl = unit >> 6, fp = (unit & 63) * 8;
            *(uint4*)(qs + (size_t)(n0 + nl) * HD + fp) = *(uint4*)&t1[nl][fp];
        }
    } else {
        int b = n0 >> 12, nl0 = n0 & 4095;
        #pragma unroll
        for (int u = 0; u < 8; u++) {
            int unit = u * 256 + tid;
            int f = unit >> 2, np = (unit & 3) * 8;
            unsigned short arr[8];
            #pragma unroll
            for (int j = 0; j < 8; j++) arr[j] = (unsigned short)t1[np + j][f];
            *(uint4*)(ksT + ((size_t)b * HD + f) * NPG + nl0 + np) = *(uint4*)arr;
        }
    }
}

// ---------------------------------------------------------------- degree
__global__ void deg_kernel(const int* __restrict__ row, int* __restrict__ deg) {
    int e = blockIdx.x * 256 + threadIdx.x;
    if (e < NEDGE) atomicAdd(&deg[row[e]], 1);
}

// ---------------------------------------------------------------- multi-block exclusive scan (+ fused dis computation)
__global__ __launch_bounds__(1024) void scan1_kernel(const int* __restrict__ deg,
                                                     int* __restrict__ row_ptr, int* __restrict__ bsum,
                                                     float* __restrict__ dis) {
    __shared__ int buf[1024];
    int g = blockIdx.x, t = threadIdx.x;
    int v = deg[g * 1024 + t];
    dis[g * 1024 + t] = v > 0 ? rsqrtf((float)v) : 0.f;
    buf[t] = v;
    __syncthreads();
    for (int off = 1; off < 1024; off <<= 1) {
        int add = (t >= off) ? buf[t - off] : 0;
        __syncthreads();
        buf[t] += add;
        __syncthreads();
    }
    row_ptr[g * 1024 + t] = buf[t] - v;
    if (t == 1023) bsum[g] = buf[1023];
}

__global__ void scan2_kernel(const int* __restrict__ bsum, int* __restrict__ boff, int* __restrict__ row_ptr) {
    int run = 0;
    for (int g = 0; g < 32; g++) { boff[g] = run; run += bsum[g]; }
    row_ptr[NTOT] = run;
}

__global__ __launch_bounds__(1024) void scan3_kernel(int* __restrict__ row_ptr, const int* __restrict__ boff) {
    row_ptr[blockIdx.x * 1024 + threadIdx.x] += boff[blockIdx.x];
}

// ---------------------------------------------------------------- per-tile degree argsort (bitonic, 128 nodes/tile)
__global__ __launch_bounds__(128) void sortperm_kernel(const int* __restrict__ row_ptr,
                                                       int* __restrict__ perm) {
    __shared__ int key[128];
    __shared__ int val[128];
    int tile = blockIdx.x;
    int t = threadIdx.x;
    int n = tile * 128 + t;
    key[t] = row_ptr[n + 1] - row_ptr[n];
    val[t] = t;
    __syncthreads();
    for (int k = 2; k <= 128; k <<= 1) {
        for (int j = k >> 1; j > 0; j >>= 1) {
            int ixj = t ^ j;
            if (ixj > t) {
                int a = key[t], b = key[ixj];
                bool up = ((t & k) == 0);
                if ((a > b) == up) {
                    key[t] = b; key[ixj] = a;
                    int va = val[t]; val[t] = val[ixj]; val[ixj] = va;
                }
            }
            __syncthreads();
        }
    }
    perm[tile * 128 + t] = val[t];
}

// ---------------------------------------------------------------- CSR scatter (packed col+weight)
__global__ void scatter_kernel(const int* __restrict__ row, const int* __restrict__ col,
                               const int* __restrict__ row_ptr, int* __restrict__ fill,
                               const float* __restrict__ dis,
                               uint2* __restrict__ ecw) {
    int e = blockIdx.x * 256 + threadIdx.x;
    if (e < NEDGE) {
        int r = row[e], c = col[e];
        int pos = row_ptr[r] + atomicAdd(&fill[r], 1);
        ecw[pos] = uint2{(unsigned)c, __float_as_uint(dis[c])};
    }
}

// ---------------------------------------------------------------- row sums over transposed layout (ksum) + fused vsumA zero
__global__ __launch_bounds__(256) void rowsum_kernel(const bf16* __restrict__ T, float* __restrict__ out,
                                                     float* __restrict__ vz) {
    if (blockIdx.x >= BATCH * HD / 4) {
        int i = (blockIdx.x - BATCH * HD / 4) * 256 + threadIdx.x;
        ((uint4*)vz)[i] = uint4{0u, 0u, 0u, 0u};
        return;
    }
    int row = blockIdx.x * 4 + (threadIdx.x >> 6);
    int lane = threadIdx.x & 63;
    const ushort4* p = (const ushort4*)(T + (size_t)row * NPG);
    float s = 0.f;
    #pragma unroll
    for (int wv = 0; wv < 16; wv++) {
        ushort4 u = p[lane + wv * 64];
        s += u2f(u.x) + u2f(u.y) + u2f(u.z) + u2f(u.w);
    }
    for (int off = 32; off > 0; off >>= 1) s += __shfl_down(s, off);
    if (lane == 0) out[row] = s;
}

// ---------------------------------------------------------------- vsum0: column sums over xbf (broadcast to heads)
__global__ __launch_bounds__(256) void colsum_kernel(const bf16* __restrict__ xbf, float* __restrict__ vsum) {
    __shared__ float buf[256];
    int b = blockIdx.x >> 3, sl = blockIdx.x & 7;
    int t = threadIdx.x;
    int d = t & 127, half = t >> 7;
    const unsigned short* p = (const unsigned short*)xbf + ((size_t)b * NPG + sl * 512 + half * 256) * DIN + d;
    float s = 0.f;
    for (int r = 0; r < 256; r++) s += u2f(p[(size_t)r * DIN]);
    buf[t] = s;
    __syncthreads();
    if (half == 0) {
        float tot = buf[d] + buf[d + 128];
        #pragma unroll
        for (int h = 0; h < NH; h++) atomicAdd(&vsum[b * HD + h * DIN + d], tot);
    }
}

// ---------------------------------------------------------------- rden = 1/(qs . ksum + n)
__global__ __launch_bounds__(256) void den_kernel(const bf16* __restrict__ qs, const float* __restrict__ ksum,
                                                  const int* __restrict__ n_nodes, float* __restrict__ rden) {
    int n = blockIdx.x;
    int b = n >> 12;
    int w = threadIdx.x >> 6, lane = threadIdx.x & 63;
    int base = w * DIN;
    float p = b2f(qs[(size_t)n * HD + base + lane])      * ksum[b * HD + base + lane]
            + b2f(qs[(size_t)n * HD + base + 64 + lane]) * ksum[b * HD + base + 64 + lane];
    for (int off = 32; off > 0; off >>= 1) p += __shfl_down(p, off);
    if (lane == 0) rden[n * NH + w] = 1.0f / (p + (float)n_nodes[b]);
}

// ---------------------------------------------------------------- kv via MFMA: split-K partials (KVSPLIT=16, streamed)
// r10: atomicAdd accumulation +50us (cross-XCD atomics). r12: last-block in-kernel
// reduction +170us (cross-XCD partial read-back at 32-block parallelism). The
// streamed-partials + separate kvredB dispatch IS the fast shape.
#define KVSPLIT 16
__global__ __launch_bounds__(512, 4) void kv_mfma_kernel(const bf16* __restrict__ ksT,
                                                         const bf16* __restrict__ vsrc,
                                                         int vld, int vhm,
                                                         float* __restrict__ partial) {
    __shared__ __align__(16) short kshT[128][72];
    __shared__ __align__(16) short vshT[128][72];
    int id = blockIdx.x;
    int b = id & 7;
    int u = id >> 3;
    int h = u >> 4;
    int s = u & 15;
    int bh = b * 4 + h;
    int blk = bh * KVSPLIT + s;
    int tid = threadIdx.x;
    int lane = tid & 63;
    int w = tid >> 6;
    int wr = w >> 1, wc = w & 1;
    int d0w = wr * 32, e0w = wc * 64;
    int l15 = lane & 15, quad = lane >> 4;

    f32x4 acc[2][4];
    #pragma unroll
    for (int i = 0; i < 2; i++)
        #pragma unroll
        for (int j = 0; j < 4; j++) acc[i][j] = f32x4{0.f, 0.f, 0.f, 0.f};

    const uint4* kg = (const uint4*)(ksT + ((size_t)bh * 128) * NPG);
    const bf16* vg = vsrc + (size_t)h * vhm;
    int n0 = s * (NPG / KVSPLIT);

    for (int c = 0; c < NPG / KVSPLIT / 64; c++) {
        int nb = n0 + c * 64;
        #pragma unroll
        for (int uu = 0; uu < 2; uu++) {
            int unit = uu * 512 + tid;
            int row = unit >> 3;
            int part = unit & 7;
            uint4 kd = kg[row * (NPG / 8) + (nb >> 3) + part];
            *(uint4*)&kshT[row][part * 8] = kd;
            int nl = unit >> 4;
            int fg = unit & 15;
            uint4 vd = *(const uint4*)(vg + (size_t)(b * NPG + nb + nl) * vld + fg * 8);
            unsigned short* sv = (unsigned short*)&vd;
            int ncol = nl ^ ((fg & 7) << 3);
            #pragma unroll
            for (int j = 0; j < 8; j++) vshT[fg * 8 + j][ncol] = (short)sv[j];
        }
        __syncthreads();
        #pragma unroll
        for (int kkstep = 0; kkstep < 2; kkstep++) {
            int kk = kkstep * 32 + quad * 8;
            short8 af[2], bfr[4];
            #pragma unroll
            for (int ti = 0; ti < 2; ti++)
                af[ti] = *(const short8*)&kshT[d0w + ti * 16 + l15][kk];
            #pragma unroll
            for (int tj = 0; tj < 4; tj++) {
                int e = e0w + tj * 16 + l15;
                bfr[tj] = *(const short8*)&vshT[e][kk ^ (((e >> 3) & 7) << 3)];
            }
            #pragma unroll
            for (int ti = 0; ti < 2; ti++)
                #pragma unroll
                for (int tj = 0; tj < 4; tj++)
                    acc[ti][tj] = __builtin_amdgcn_mfma_f32_16x16x32_bf16(af[ti], bfr[tj], acc[ti][tj], 0, 0, 0);
        }
        __syncthreads();
    }
    float* p = partial + (size_t)blk * (128 * 128);
    #pragma unroll
    for (int ti = 0; ti < 2; ti++)
        #pragma unroll
        for (int tj = 0; tj < 4; tj++)
            #pragma unroll
            for (int r = 0; r < 4; r++) {
                int row = d0w + ti * 16 + quad * 4 + r;
                int col = e0w + tj * 16 + l15;
                p[row * 128 + col] = acc[ti][tj][r];
            }
}

// ---------------------------------------------------------------- reduce split-K partials -> kvB (bf16); block 256 zeroes vsumN
// (fused vsN zero saves ~11us of per-iter launch bubbles — verified r11)
__global__ __launch_bounds__(256) void kvredB_kernel(const float* __restrict__ partial, bf16* __restrict__ kvB,
                                                     float* __restrict__ vsumN) {
    if (blockIdx.x == 256) {
        ((uint4*)vsumN)[threadIdx.x] = uint4{0u, 0u, 0u, 0u};
        ((uint4*)vsumN)[256 + threadIdx.x] = uint4{0u, 0u, 0u, 0u};
        ((uint4*)vsumN)[512 + threadIdx.x] = uint4{0u, 0u, 0u, 0u};
        ((uint4*)vsumN)[768 + threadIdx.x] = uint4{0u, 0u, 0u, 0u};
        return;
    }
    __shared__ __align__(16) short t[16][136];
    int blk = blockIdx.x;
    int bh = blk >> 3;
    int e0 = (blk & 7) * 16;
    int tid = threadIdx.x;
    int el = tid & 15;
    int dc = tid >> 4;
    const float* p = partial + (size_t)bh * (KVSPLIT * 16384);
    #pragma unroll
    for (int j = 0; j < 8; j++) {
        int d = dc * 8 + j;
        int idx = d * 128 + e0 + el;
        float s = 0.f;
        #pragma unroll
        for (int sl = 0; sl < KVSPLIT; sl++) s += p[sl * 16384 + idx];
        t[el][d] = (short)f2u(s);
    }
    __syncthreads();
    int e = tid >> 4, dp = (tid & 15) * 8;
    *(uint4*)((unsigned short*)kvB + (size_t)bh * 16384 + (e0 + e) * 128 + dp) = *(uint4*)&t[e][dp];
}

// ---------------------------------------------------------------- gather FMA helper
static __device__ __forceinline__ void acc8(float* g, uint4 v, float w) {
    unsigned short* sv = (unsigned short*)&v;
    #pragma unroll
    for (int k = 0; k < 8; k++) g[k] += w * u2f(sv[k]);
}

// ---------------------------------------------------------------- fused GCN-gather + attn MFMA + combine + store
// PROVEN BEST (r5/r11: 55us/dispatch). 2-deep pipeline, 4 thr/node, 128 nodes/block,
// est staging EMAX 1536, degree-sort perm, lb(512,2).
// Locked lessons: lb(512,6) spills (r3); no est staging +7us (r6); 8 thr/node -35% (r7);
// 4-deep -> VGPR 96 -> 2 blk/CU -21% (r8); NT hints +8us (r9); kv atomics +50us (r10);
// in-kernel cross-XCD reduction +170us (r12).
#define EMAX 1536
__global__ __launch_bounds__(512, 2) void gcn_attn_kernel(const bf16* __restrict__ qs,
                                                          const bf16* __restrict__ kvB,
                                                          const bf16* __restrict__ gsrc,
                                                          int gld, int ghm,
                                                          const int* __restrict__ row_ptr,
                                                          const int* __restrict__ perm,
                                                          const uint2* __restrict__ ecw,
                                                          const float* __restrict__ dis,
                                                          const float* __restrict__ vsum,   // current iter
                                                          const float* __restrict__ rden,
                                                          bf16* __restrict__ curN,
                                                          float* __restrict__ vsumN) {      // next iter (atomic)
    __shared__ __align__(16) short t1[128][136];
    __shared__ __align__(8) uint2 est[EMAX];
    int id = blockIdx.x;
    int b = id & 7;
    int u = id >> 3;
    int h = u >> 5;
    int m = u & 31;
    int bh = b * 4 + h;
    int n0 = b * NPG + m * 128;
    int tid = threadIdx.x;
    int lane = tid & 63, w = tid >> 6;
    int wr = w >> 1, wc = w & 1;
    int e0w = wc * 64;
    int l15 = lane & 15, quad = lane >> 4;

    // phase A0: stage this block's edge list into LDS (coalesced)
    int ebase = row_ptr[n0];
    int ecnt = row_ptr[n0 + 128] - ebase;
    int scnt = ecnt < EMAX ? ecnt : EMAX;
    for (int i = tid; i < scnt; i += 512) est[i] = ecw[ebase + i];
    __syncthreads();

    // phase A: GCN gather, 2-edge-deep pipelined, nodes in ascending-degree order
    {
        int nl = perm[n0 + (tid >> 2)];
        int sub = tid & 3;
        int n = n0 + nl;
        int start = row_ptr[n] - ebase;
        int end   = row_ptr[n + 1] - ebase;
        int lend  = end < scnt ? end : scnt;
        float g[32];
        #pragma unroll
        for (int i = 0; i < 32; i++) g[i] = 0.f;
        const bf16* gbase = gsrc + (size_t)h * ghm + sub * 32;

        int cA = 0, cB = 0; float wA = 0.f, wB = 0.f;
        if (start < lend)     { uint2 p = est[start];     cA = (int)p.x; wA = __uint_as_float(p.y); }
        if (start + 1 < lend) { uint2 p = est[start + 1]; cB = (int)p.x; wB = __uint_as_float(p.y); }
        uint4 vA0, vA1, vA2, vA3, vB0, vB1, vB2, vB3;
        {
            const uint4* p = (const uint4*)(gbase + (size_t)cA * gld);
            vA0 = p[0]; vA1 = p[1]; vA2 = p[2]; vA3 = p[3];
        }
        {
            const uint4* p = (const uint4*)(gbase + (size_t)cB * gld);
            vB0 = p[0]; vB1 = p[1]; vB2 = p[2]; vB3 = p[3];
        }
        for (int j = start; j < lend; j += 2) {
            int cC = 0, cD = 0; float wC = 0.f, wD = 0.f;
            if (j + 2 < lend) { uint2 p = est[j + 2]; cC = (int)p.x; wC = __uint_as_float(p.y); }
            if (j + 3 < lend) { uint2 p = est[j + 3]; cD = (int)p.x; wD = __uint_as_float(p.y); }
            acc8(g +  0, vA0, wA); acc8(g +  8, vA1, wA);
            acc8(g + 16, vA2, wA); acc8(g + 24, vA3, wA);
            {
                const uint4* p = (const uint4*)(gbase + (size_t)cC * gld);
                vA0 = p[0]; vA1 = p[1]; vA2 = p[2]; vA3 = p[3];
            }
            acc8(g +  0, vB0, wB); acc8(g +  8, vB1, wB);
            acc8(g + 16, vB2, wB); acc8(g + 24, vB3, wB);
            {
                const uint4* p = (const uint4*)(gbase + (size_t)cD * gld);
                vB0 = p[0]; vB1 = p[1]; vB2 = p[2]; vB3 = p[3];
            }
            wA = wC; wB = wD;
        }
        int fstart = start > lend ? start : lend;
        for (int j = fstart; j < end; j++) {
            uint2 pe = ecw[ebase + j];
            int c = (int)pe.x; float ww = __uint_as_float(pe.y);
            const uint4* p = (const uint4*)(gbase + (size_t)c * gld);
            acc8(g +  0, p[0], ww); acc8(g +  8, p[1], ww);
            acc8(g + 16, p[2], ww); acc8(g + 24, p[3], ww);
        }

        float dn = dis[n];
        int sw = (nl >> 3) & 7;
        #pragma unroll
        for (int q = 0; q < 4; q++) {
            unsigned short arr[8];
            #pragma unroll
            for (int k = 0; k < 8; k++) arr[k] = f2u(g[q * 8 + k] * dn);
            int fb = (sub * 4 + q) ^ sw;
            *(uint4*)&t1[nl][fb * 8] = *(uint4*)arr;
        }
    }

    // phase B: MFMA q . kv (independent of t1)
    f32x4 acc[2][4];
    #pragma unroll
    for (int i = 0; i < 2; i++)
        #pragma unroll
        for (int j = 0; j < 4; j++) acc[i][j] = f32x4{0.f, 0.f, 0.f, 0.f};

    const bf16* Aq = qs + (size_t)n0 * HD + h * DIN;
    const unsigned short* Bk = (const unsigned short*)kvB + (size_t)bh * 16384;
    #pragma unroll
    for (int ks = 0; ks < 4; ks++) {
        int kk = ks * 32 + quad * 8;
        short8 af[2], bfr[4];
        #pragma unroll
        for (int ti = 0; ti < 2; ti++)
            af[ti] = *(const short8*)(Aq + (size_t)(wr * 32 + ti * 16 + l15) * HD + kk);
        #pragma unroll
        for (int tj = 0; tj < 4; tj++)
            bfr[tj] = *(const short8*)(Bk + (e0w + tj * 16 + l15) * 128 + kk);
        #pragma unroll
        for (int ti = 0; ti < 2; ti++)
            #pragma unroll
            for (int tj = 0; tj < 4; tj++)
                acc[ti][tj] = __builtin_amdgcn_mfma_f32_16x16x32_bf16(af[ti], bfr[tj], acc[ti][tj], 0, 0, 0);
    }
    __syncthreads();

    // phase C: combine + register-level column sums for next-iter vsum
    #pragma unroll
    for (int tj = 0; tj < 4; tj++) {
        int el = e0w + tj * 16 + l15;
        float vs = vsum[b * HD + h * DIN + el];
        float cs = 0.f;
        #pragma unroll
        for (int ti = 0; ti < 2; ti++) {
            int nlb = wr * 32 + ti * 16 + quad * 4;
            #pragma unroll
            for (int r = 0; r < 4; r++) {
                int nl = nlb + r;
                int sw = (nl >> 3) & 7;
                int pc = (((el >> 3) ^ sw) * 8) | (el & 7);
                float attnv = (acc[ti][tj][r] + vs) * rden[(size_t)(n0 + nl) * NH + h];
                float g = u2f((unsigned short)t1[nl][pc]);
                float val = 0.5f * g + 0.5f * attnv;
                t1[nl][pc] = (short)f2u(val);
                cs += val;
            }
        }
        cs += __shfl_xor(cs, 16);
        cs += __shfl_xor(cs, 32);
        if (quad == 0) atomicAdd(&vsumN[b * HD + h * DIN + el], cs);
    }
    __syncthreads();

    // phase D: curN store only
    {
        bf16* dstn = curN + (size_t)n0 * HD + h * DIN;
        #pragma unroll
        for (int uu = 0; uu < 4; uu++) {
            int unit = uu * 512 + tid;
            int nl = unit >> 4, fb = unit & 15;
            int sw = (nl >> 3) & 7;
            uint4 v = *(uint4*)&t1[nl][(fb ^ sw) * 8];
            *(uint4*)(dstn + (size_t)nl * HD + fb * 8) = v;
        }
    }
}

// ---------------------------------------------------------------- output projection via MFMA, fused acc = xh + sum(cur_k)
__global__ __launch_bounds__(256, 4) void out_mfma_kernel(const bf16* __restrict__ xbf,
                                                          const bf16* __restrict__ c1,
                                                          const bf16* __restrict__ c2,
                                                          const bf16* __restrict__ c3,
                                                          const bf16* __restrict__ c4,
                                                          const bf16* __restrict__ Wobf,
                                                          const float* __restrict__ Wo_b,
                                                          float* __restrict__ out) {
    __shared__ __align__(16) short ash[32][520];
    int n0 = blockIdx.x * 32;
    int tid = threadIdx.x;
    int lane = tid & 63, w = tid >> 6;
    int l15 = lane & 15, quad = lane >> 4;

    #pragma unroll 4
    for (int uu = 0; uu < 8; uu++) {
        int unit = uu * 256 + tid;
        int row = unit >> 6, cg = unit & 63;
        int col = cg * 8;
        size_t rbase = (size_t)(n0 + row);
        uint4 vx = *(const uint4*)(xbf + rbase * DIN + (col & 127));
        uint4 v1 = *(const uint4*)(c1 + rbase * HD + col);
        uint4 v2 = *(const uint4*)(c2 + rbase * HD + col);
        uint4 v3 = *(const uint4*)(c3 + rbase * HD + col);
        uint4 v4 = *(const uint4*)(c4 + rbase * HD + col);
        unsigned short* px = (unsigned short*)&vx;
        unsigned short* p1 = (unsigned short*)&v1;
        unsigned short* p2 = (unsigned short*)&v2;
        unsigned short* p3 = (unsigned short*)&v3;
        unsigned short* p4 = (unsigned short*)&v4;
        unsigned short o[8];
        #pragma unroll
        for (int j = 0; j < 8; j++)
            o[j] = f2u(u2f(px[j]) + u2f(p1[j]) + u2f(p2[j]) + u2f(p3[j]) + u2f(p4[j]));
        *(uint4*)&ash[row][col] = *(uint4*)o;
    }
    __syncthreads();

    f32x4 acc[2][2];
    #pragma unroll
    for (int i = 0; i < 2; i++)
        #pragma unroll
        for (int j = 0; j < 2; j++) acc[i][j] = f32x4{0.f, 0.f, 0.f, 0.f};

    #pragma unroll
    for (int ks = 0; ks < 16; ks++) {
        int kk = ks * 32 + quad * 8;
        short8 af[2], bfr[2];
        #pragma unroll
        for (int ti = 0; ti < 2; ti++)
            af[ti] = *(const short8*)&ash[ti * 16 + l15][kk];
        #pragma unroll
        for (int tj = 0; tj < 2; tj++)
            bfr[tj] = *(const short8*)(Wobf + (size_t)(w * 32 + tj * 16 + l15) * HD + kk);
        #pragma unroll
        for (int ti = 0; ti < 2; ti++)
            #pragma unroll
            for (int tj = 0; tj < 2; tj++)
                acc[ti][tj] = __builtin_amdgcn_mfma_f32_16x16x32_bf16(af[ti], bfr[tj], acc[ti][tj], 0, 0, 0);
    }

    #pragma unroll
    for (int tj = 0; tj < 2; tj++) {
        int col = w * 32 + tj * 16 + l15;
        float bv = Wo_b[col];
        #pragma unroll
        for (int ti = 0; ti < 2; ti++) {
            int rowb = ti * 16 + quad * 4;
            #pragma unroll
            for (int r = 0; r < 4; r++)
                out[(size_t)(n0 + rowb + r) * DOUTF + col] = (acc[ti][tj][r] + bv) * 0.25f;
        }
    }
}

// ================================================================ launch
extern "C" void kernel_launch(void* const* d_in, const int* in_sizes, int n_in,
                              void* d_out, int out_size, void* d_ws, size_t ws_size,
                              hipStream_t stream) {
    const float* x     = (const float*)d_in[0];
    const float* Wq_w  = (const float*)d_in[1];
    const float* Wq_b  = (const float*)d_in[2];
    const float* Wk_w  = (const float*)d_in[3];
    const float* Wk_b  = (const float*)d_in[4];
    const float* Wo_w  = (const float*)d_in[5];
    const float* Wo_b  = (const float*)d_in[6];
    const int*   edge  = (const int*)d_in[7];
    const int*   n_nod = (const int*)d_in[8];
    float* out = (float*)d_out;
    const int* erow = edge;
    const int* ecol = edge + NEDGE;

    char* w = (char*)d_ws;
    auto alloc = [&](size_t bytes) -> char* {
        char* p = w;
        w += (bytes + 255) & ~(size_t)255;
        return p;
    };
    bf16*  qs      = (bf16*) alloc((size_t)NTOT * HD * 2);            // 32 MiB
    bf16*  ksT     = (bf16*) alloc((size_t)NTOT * HD * 2);            // 32 MiB
    bf16*  cur1    = (bf16*) alloc((size_t)NTOT * HD * 2);            // 32 MiB
    bf16*  cur2    = (bf16*) alloc((size_t)NTOT * HD * 2);            // 32 MiB
    bf16*  cur3    = (bf16*) alloc((size_t)NTOT * HD * 2);            // 32 MiB
    bf16*  cur4    = (bf16*) alloc((size_t)NTOT * HD * 2);            // 32 MiB
    bf16*  xbf     = (bf16*) alloc((size_t)NTOT * DIN * 2);           // 8 MiB (persistent)
    float* partial = (float*)alloc((size_t)32 * KVSPLIT * 16384 * 4); // 32 MiB (aliased in setup)
    bf16*  kvB     = (bf16*) alloc((size_t)32 * 16384 * 2);           // 1 MiB
    bf16*  Wobf    = (bf16*) alloc(DOUTF * HD * 2);                   // 128 KiB
    int*   degfill = (int*)  alloc(2 * NTOT * 4);
    float* dis     = (float*)alloc(NTOT * 4);
    int*   row_ptr = (int*)  alloc((NTOT + 1) * 4);
    int*   perm    = (int*)  alloc(NTOT * 4);
    uint2* ecw     = (uint2*)alloc((size_t)NEDGE * 8);
    float* ksum    = (float*)alloc(BATCH * HD * 4);
    float* vsumA   = (float*)alloc(BATCH * HD * 4);
    float* vsumB   = (float*)alloc(BATCH * HD * 4);
    float* rden    = (float*)alloc((size_t)NTOT * NH * 4);
    int*   bsum    = (int*)  alloc(32 * 4);
    int*   boff    = (int*)  alloc(32 * 4);
    int* deg  = degfill;
    int* fill = degfill + NTOT;
    // setup-only weight buffers aliased onto partial (dead before first kv_mfma)
    bf16* Wqbf = (bf16*)partial;
    bf16* Wkbf = Wqbf + (size_t)HD * DIN;
    // total ~216 MiB

    // x conversion + degfill zero fused (tail blocks)
    cvtbf_zero_kernel<<<2048 + 64, 256, 0, stream>>>(x, xbf, NTOT * DIN, 2048,
                                                     (uint4*)degfill, 2 * NTOT / 4);
    cvtbf_kernel<<<HD * DIN / 8 / 256, 256, 0, stream>>>(Wq_w, Wqbf, HD * DIN);
    cvtbf_kernel<<<HD * DIN / 8 / 256, 256, 0, stream>>>(Wk_w, Wkbf, HD * DIN);
    cvtbf_kernel<<<DOUTF * HD / 8 / 256, 256, 0, stream>>>(Wo_w, Wobf, DOUTF * HD);

    proj2_mfma_kernel<<<2 * (NTOT / 32), 256, 0, stream>>>(xbf, Wqbf, Wq_b, qs, Wkbf, Wk_b, ksT);

    deg_kernel<<<NEDGE / 256, 256, 0, stream>>>(erow, deg);
    scan1_kernel<<<32, 1024, 0, stream>>>(deg, row_ptr, bsum, dis);
    scan2_kernel<<<1, 1, 0, stream>>>(bsum, boff, row_ptr);
    scan3_kernel<<<32, 1024, 0, stream>>>(row_ptr, boff);
    sortperm_kernel<<<NTOT / 128, 128, 0, stream>>>(row_ptr, perm);
    scatter_kernel<<<NEDGE / 256, 256, 0, stream>>>(erow, ecol, row_ptr, fill, dis, ecw);

    rowsum_kernel<<<BATCH * HD / 4 + 4, 256, 0, stream>>>(ksT, ksum, vsumA);
    den_kernel<<<NTOT, 256, 0, stream>>>(qs, ksum, n_nod, rden);
    colsum_kernel<<<64, 256, 0, stream>>>(xbf, vsumA);

    bf16* curs[4] = { cur1, cur2, cur3, cur4 };
    float* vs = vsumA;
    float* vsN = vsumB;
    for (int it = 0; it < KORDER; it++) {
        const bf16* src = (it == 0) ? xbf : curs[it - 1];
        int ld = (it == 0) ? DIN : HD;
        int hm = (it == 0) ? 0 : DIN;
        kv_mfma_kernel<<<32 * KVSPLIT, 512, 0, stream>>>(ksT, src, ld, hm, partial);
        kvredB_kernel<<<257, 256, 0, stream>>>(partial, kvB, vsN);
        gcn_attn_kernel<<<32 * 32, 512, 0, stream>>>(qs, kvB, src, ld, hm, row_ptr, perm, ecw, dis,
                                                     vs, rden, curs[it], vsN);
        float* tf = vs; vs = vsN; vsN = tf;
    }

    out_mfma_kernel<<<NTOT / 32, 256, 0, stream>>>(xbf, cur1, cur2, cur3, cur4, Wobf, Wo_b, out);

    (void)in_sizes; (void)n_in; (void)out_size; (void)ws_size;
}